// Round 2
// 828.306 us; speedup vs baseline: 1.1137x; 1.1137x over previous
//
#include <hip/hip_runtime.h>

// IrradianceVolumes: out[i,c] = relu( sum_j sh_j(normal_i) * trilerp(coeff[...,j,c], point_i) )
// coeff: [128,128,128,16,3] f32 (403 MB), points/normals: [2M,3] f32, out: [2M,3] f32.
//
// Round 6 (= round 5 re-run; round-5 bench died to a container/infra failure, not a
// kernel failure — no pytest mismatch, no counters, and the design obeys all
// graph-capture rules with a 16.3 MB workspace < proven 17.4 MB budget):
//
//  - 3-pass counting sort (hist + single-block scan + atomic-return scatter), which
//    was ~650us of the 922us round-4 total, replaced by a ONE-pass capacity-binned
//    scatter:
//      * each (bin, replica) gets a fixed CAP=104 slot segment -> slot base is
//        compile-time arithmetic, no histogram, no prefix scan.
//      * counters replicated 4x (replica = wave-uniform (i>>6)&3) and padded to a
//        64B line: same-address atomic chains drop 256 -> ~61 ops/address.
//      * Poisson(lambda=64) vs CAP=104 -> ~0.1 expected overflow events total;
//        overflows go to a 128K-entry list handled by a cleanup kernel. If even
//        that list overflows (adversarial input), a flag makes the cleanup kernel
//        re-sweep all points and compute the unplaced ones directly. Zero cost
//        when the flag is 0.
//  - scatter_kernel slimmed: no coeff/normals/out args, no fat inline fallback.
//  - main_kernel structurally unchanged from the measured 270us version (same
//    4x8x8 bins, 5x9x9 halo, 77,760 B LDS, 2 blocks/CU); walks the 4 replica
//    segments per bin.

constexpr int RES = 128;
constexpr int D2 = 16;
constexpr int CSTRIDE = D2 * 3;       // 48 floats per cell
constexpr int CELL_F4 = CSTRIDE / 4;  // 12 float4 per cell

// bins: x split by 4 (shift 2), y/z by 8 (shift 3)
constexpr int NBX = 32, NBY = 16, NBZ = 16;
constexpr int NBINS = NBX * NBY * NBZ;     // 8192
constexpr int HX = 5, HY = 9, HZ = 9;      // halo cells per axis
constexpr int TOT_F4 = HX * HY * HZ * CELL_F4; // 4860 float4 = 77,760 B
constexpr int MAIN_THREADS = 256;
constexpr int LOAD_ITERS = (TOT_F4 + MAIN_THREADS - 1) / MAIN_THREADS; // 19

constexpr int REPL = 4;          // counter/segment replicas per bin
constexpr int CAP = 104;         // slots per (bin, replica); lambda=64 -> P(ovf)~1e-6
constexpr int CNT_PAD = 16;      // ints per padded counter (64 B line)
constexpr int OVF_CAP = 131072;  // overflow list capacity (512 KB)

__device__ __forceinline__ void grid_coords(const float* aabb, float px, float py, float pz,
                                            int& ix, int& iy, int& iz,
                                            float& fx, float& fy, float& fz)
{
    const float a0 = aabb[0], a1 = aabb[1], a2 = aabb[2];
    const float b0 = aabb[3], b1 = aabb[4], b2 = aabb[5];
    float gx = (px - a0) / (b0 - a0) * (float)(RES - 1);
    float gy = (py - a1) / (b1 - a1) * (float)(RES - 1);
    float gz = (pz - a2) / (b2 - a2) * (float)(RES - 1);
    gx = fminf(fmaxf(gx, 0.0f), (float)(RES - 1));
    gy = fminf(fmaxf(gy, 0.0f), (float)(RES - 1));
    gz = fminf(fmaxf(gz, 0.0f), (float)(RES - 1));
    ix = min((int)floorf(gx), RES - 2);
    iy = min((int)floorf(gy), RES - 2);
    iz = min((int)floorf(gz), RES - 2);
    fx = gx - (float)ix;
    fy = gy - (float)iy;
    fz = gz - (float)iz;
}

__device__ __forceinline__ int bin_of(int ix, int iy, int iz)
{
    return (((ix >> 2) * NBY) + (iy >> 3)) * NBZ + (iz >> 3);
}

__device__ __forceinline__ void sh_basis(float nx, float ny, float nz, float* sh)
{
    const float xx = nx * nx, yy = ny * ny, zz = nz * nz;
    const float xy = nx * ny, yz = ny * nz, xz = nx * nz;
    sh[0]  = 0.28209479177387814f;
    sh[1]  = -0.4886025119029199f * ny;
    sh[2]  = 0.4886025119029199f * nz;
    sh[3]  = -0.4886025119029199f * nx;
    sh[4]  = 1.0925484305920792f * xy;
    sh[5]  = -1.0925484305920792f * yz;
    sh[6]  = 0.31539156525252005f * (2.0f * zz - xx - yy);
    sh[7]  = -1.0925484305920792f * xz;
    sh[8]  = 0.5462742152960396f * (xx - yy);
    sh[9]  = -0.5900435899266435f * ny * (3.0f * xx - yy);
    sh[10] = 2.890611442640554f * xy * nz;
    sh[11] = -0.4570457994644658f * ny * (4.0f * zz - xx - yy);
    sh[12] = 0.3731763325901154f * nz * (2.0f * zz - 3.0f * xx - 3.0f * yy);
    sh[13] = -0.4570457994644658f * nx * (4.0f * zz - xx - yy);
    sh[14] = 1.445305721320277f * nz * (xx - yy);
    sh[15] = -0.5900435899266435f * nx * (xx - 3.0f * yy);
}

// Fully-direct per-point evaluation from global memory (fallback / overflow path).
__device__ void compute_point_global(
    const float* __restrict__ coeff,
    const float* __restrict__ aabb,
    const float* __restrict__ points,
    const float* __restrict__ normals,
    float* __restrict__ out, int i)
{
    const float px = points[3 * i + 0], py = points[3 * i + 1], pz = points[3 * i + 2];
    const float nx = normals[3 * i + 0], ny = normals[3 * i + 1], nz = normals[3 * i + 2];
    int ix, iy, iz; float fx, fy, fz;
    grid_coords(aabb, px, py, pz, ix, iy, iz, fx, fy, fz);
    float sh[D2];
    sh_basis(nx, ny, nz, sh);
    const float wz0 = 1.0f - fz, wz1 = fz;
    float acc0 = 0.0f, acc1 = 0.0f, acc2 = 0.0f;
#pragma unroll
    for (int dx = 0; dx < 2; ++dx) {
        const float wx = dx ? fx : 1.0f - fx;
#pragma unroll
        for (int dy = 0; dy < 2; ++dy) {
            const float wxy = wx * (dy ? fy : 1.0f - fy);
            const int cell = (((ix + dx) * RES + (iy + dy)) * RES + iz) * CSTRIDE;
            const float4* __restrict__ cp = (const float4*)(coeff + cell);
            union { float4 q[24]; float v[96]; } u;
#pragma unroll
            for (int kk = 0; kk < 24; ++kk) u.q[kk] = cp[kk];
            float s00 = 0.f, s01 = 0.f, s02 = 0.f;
            float s10 = 0.f, s11 = 0.f, s12 = 0.f;
#pragma unroll
            for (int j = 0; j < D2; ++j) {
                const float s = sh[j];
                s00 = fmaf(s, u.v[3 * j + 0], s00);
                s01 = fmaf(s, u.v[3 * j + 1], s01);
                s02 = fmaf(s, u.v[3 * j + 2], s02);
                s10 = fmaf(s, u.v[48 + 3 * j + 0], s10);
                s11 = fmaf(s, u.v[48 + 3 * j + 1], s11);
                s12 = fmaf(s, u.v[48 + 3 * j + 2], s12);
            }
            const float w0 = wxy * wz0, w1 = wxy * wz1;
            acc0 = fmaf(w0, s00, fmaf(w1, s10, acc0));
            acc1 = fmaf(w0, s01, fmaf(w1, s11, acc1));
            acc2 = fmaf(w0, s02, fmaf(w1, s12, acc2));
        }
    }
    out[3 * i + 0] = fmaxf(acc0, 0.0f);
    out[3 * i + 1] = fmaxf(acc1, 0.0f);
    out[3 * i + 2] = fmaxf(acc2, 0.0f);
}

// ---------------- pass 1 (the ONLY sort pass): capacity-binned scatter ----------------
// Placement outcome per point i:
//   slot in (bin,rep) segment  -> processed by main_kernel
//   overflow list entry        -> processed by overflow_kernel
//   neither (ovf list full)    -> dropped_flag set; overflow_kernel re-sweeps all
//                                 points and computes unplaced ones directly.
__global__ __launch_bounds__(256) void scatter_kernel(
    const float* __restrict__ aabb,
    const float* __restrict__ points,
    int* __restrict__ cnt_p,      // NBINS * REPL * CNT_PAD, pre-zeroed
    int* __restrict__ slots,      // NBINS * REPL * CAP
    int* __restrict__ ovf_cnt,    // [0]=count, [1]=dropped flag; pre-zeroed
    int* __restrict__ ovf,        // OVF_CAP
    int n)
{
    const int i = blockIdx.x * blockDim.x + threadIdx.x;
    if (i >= n) return;
    int ix, iy, iz; float fx, fy, fz;
    grid_coords(aabb, points[3 * i + 0], points[3 * i + 1], points[3 * i + 2],
                ix, iy, iz, fx, fy, fz);
    const int bin = bin_of(ix, iy, iz);
    const int rep = (i >> 6) & (REPL - 1);   // wave-uniform replica choice
    const int g = bin * REPL + rep;
    const int pos = atomicAdd(&cnt_p[g * CNT_PAD], 1);
    if (pos < CAP) {
        slots[g * CAP + pos] = i;
    } else {
        const int o = atomicAdd(&ovf_cnt[0], 1);
        if (o < OVF_CAP) ovf[o] = i;
        else ovf_cnt[1] = 1;  // adversarial input: signal full re-sweep
    }
}

// ---------------- pass 2: one block per bin, LDS-staged gather ----------------
__global__ __launch_bounds__(MAIN_THREADS) void main_kernel(
    const float* __restrict__ coeff,
    const float* __restrict__ aabb,
    const float* __restrict__ points,
    const float* __restrict__ normals,
    const int* __restrict__ cnt_p,
    const int* __restrict__ slots,
    float* __restrict__ out)
{
    extern __shared__ char smem[];
    float4* lds4 = (float4*)smem;

    const int bin = blockIdx.x;
    const int c0 = min(cnt_p[(bin * REPL + 0) * CNT_PAD], CAP);
    const int c1 = min(cnt_p[(bin * REPL + 1) * CNT_PAD], CAP);
    const int c2 = min(cnt_p[(bin * REPL + 2) * CNT_PAD], CAP);
    const int c3 = min(cnt_p[(bin * REPL + 3) * CNT_PAD], CAP);
    const int tot = c0 + c1 + c2 + c3;
    if (tot == 0) return;

    const int bx = bin / (NBY * NBZ);
    const int by = (bin / NBZ) % NBY;
    const int bz = bin % NBZ;
    const int x0 = bx << 2;
    const int y0 = by << 3;
    const int z0 = bz << 3;

    const int tid = threadIdx.x;
    const float4* __restrict__ coeff4 = (const float4*)coeff;

    // ---- stage 5x9x9-cell halo region into LDS (lane-contiguous, coalesced) ----
#pragma unroll
    for (int k = 0; k < LOAD_ITERS; ++k) {
        const int u = tid + k * MAIN_THREADS;
        if (u < TOT_F4) {
            int cx = u / (HY * HZ * CELL_F4);            // /972
            int r1 = u - cx * (HY * HZ * CELL_F4);
            int cy = r1 / (HZ * CELL_F4);                // /108
            int r2 = r1 - cy * (HZ * CELL_F4);
            int cz = r2 / CELL_F4;                       // /12
            int kk = r2 - cz * CELL_F4;
            int xg = min(x0 + cx, RES - 1);
            int yg = min(y0 + cy, RES - 1);
            int zg = min(z0 + cz, RES - 1);
            lds4[u] = coeff4[((xg * RES + yg) * RES + zg) * CELL_F4 + kk];
        }
    }
    __syncthreads();

    // ---- compute this bin's points from LDS ----
    for (int t = tid; t < tot; t += MAIN_THREADS) {
        int k = t, r = 0;
        if (k >= c0) { k -= c0; r = 1;
            if (k >= c1) { k -= c1; r = 2;
                if (k >= c2) { k -= c2; r = 3; } } }
        const int i = slots[(bin * REPL + r) * CAP + k];

        const float px = points[3 * i + 0];
        const float py = points[3 * i + 1];
        const float pz = points[3 * i + 2];
        const float nx = normals[3 * i + 0];
        const float ny = normals[3 * i + 1];
        const float nz = normals[3 * i + 2];

        int ix, iy, iz; float fx, fy, fz;
        grid_coords(aabb, px, py, pz, ix, iy, iz, fx, fy, fz);
        const int lx = ix - x0, ly = iy - y0, lz = iz - z0;

        float sh[D2];
        sh_basis(nx, ny, nz, sh);

        const float wz0 = 1.0f - fz, wz1 = fz;
        float acc0 = 0.0f, acc1 = 0.0f, acc2 = 0.0f;

#pragma unroll
        for (int dx = 0; dx < 2; ++dx) {
            const float wx = dx ? fx : 1.0f - fx;
#pragma unroll
            for (int dy = 0; dy < 2; ++dy) {
                const float wxy = wx * (dy ? fy : 1.0f - fy);
                const int lcell = (((lx + dx) * HY + (ly + dy)) * HZ + lz) * CELL_F4;
                union { float4 q[24]; float v[96]; } u;
#pragma unroll
                for (int kk = 0; kk < 24; ++kk) u.q[kk] = lds4[lcell + kk];

                float s00 = 0.f, s01 = 0.f, s02 = 0.f;
                float s10 = 0.f, s11 = 0.f, s12 = 0.f;
#pragma unroll
                for (int j = 0; j < D2; ++j) {
                    const float s = sh[j];
                    s00 = fmaf(s, u.v[3 * j + 0], s00);
                    s01 = fmaf(s, u.v[3 * j + 1], s01);
                    s02 = fmaf(s, u.v[3 * j + 2], s02);
                    s10 = fmaf(s, u.v[48 + 3 * j + 0], s10);
                    s11 = fmaf(s, u.v[48 + 3 * j + 1], s11);
                    s12 = fmaf(s, u.v[48 + 3 * j + 2], s12);
                }
                const float w0 = wxy * wz0, w1 = wxy * wz1;
                acc0 = fmaf(w0, s00, fmaf(w1, s10, acc0));
                acc1 = fmaf(w0, s01, fmaf(w1, s11, acc1));
                acc2 = fmaf(w0, s02, fmaf(w1, s12, acc2));
            }
        }

        out[3 * i + 0] = fmaxf(acc0, 0.0f);
        out[3 * i + 1] = fmaxf(acc1, 0.0f);
        out[3 * i + 2] = fmaxf(acc2, 0.0f);
    }
}

// ---------------- pass 3: process overflow list (expected ~0 entries) ----------------
__global__ __launch_bounds__(256) void overflow_kernel(
    const float* __restrict__ coeff,
    const float* __restrict__ aabb,
    const float* __restrict__ points,
    const float* __restrict__ normals,
    const int* __restrict__ ovf_cnt,
    const int* __restrict__ ovf,
    const int* __restrict__ cnt_p,   // for the adversarial re-sweep only
    const int* __restrict__ slots,
    float* __restrict__ out,
    int n)
{
    const int m = min(ovf_cnt[0], OVF_CAP);
    for (int t = blockIdx.x * blockDim.x + threadIdx.x; t < m; t += gridDim.x * blockDim.x)
        compute_point_global(coeff, aabb, points, normals, out, ovf[t]);

    // Adversarial-input path (ovf list overflowed): find unplaced points by
    // re-deriving each point's slot membership. ovf_cnt[1]==0 on all sane inputs.
    if (ovf_cnt[1]) {
        for (int i = blockIdx.x * blockDim.x + threadIdx.x; i < n; i += gridDim.x * blockDim.x) {
            int ix, iy, iz; float fx, fy, fz;
            grid_coords(aabb, points[3 * i + 0], points[3 * i + 1], points[3 * i + 2],
                        ix, iy, iz, fx, fy, fz);
            const int g = bin_of(ix, iy, iz) * REPL + ((i >> 6) & (REPL - 1));
            const int c = min(cnt_p[g * CNT_PAD], CAP);
            bool placed = false;
            for (int k = 0; k < c && !placed; ++k) placed = (slots[g * CAP + k] == i);
            for (int k = 0; k < m && !placed; ++k)  placed = (ovf[k] == i);
            if (!placed) compute_point_global(coeff, aabb, points, normals, out, i);
        }
    }
}

// ---------------- fallback: direct, unsorted ----------------
__global__ __launch_bounds__(256) void direct_kernel(
    const float* __restrict__ coeff,
    const float* __restrict__ aabb,
    const float* __restrict__ points,
    const float* __restrict__ normals,
    float* __restrict__ out,
    int n)
{
    const int i = blockIdx.x * blockDim.x + threadIdx.x;
    if (i >= n) return;
    compute_point_global(coeff, aabb, points, normals, out, i);
}

extern "C" void kernel_launch(void* const* d_in, const int* in_sizes, int n_in,
                              void* d_out, int out_size, void* d_ws, size_t ws_size,
                              hipStream_t stream) {
    const float* coeff   = (const float*)d_in[0];
    const float* aabb    = (const float*)d_in[1];
    const float* points  = (const float*)d_in[2];
    const float* normals = (const float*)d_in[3];
    float* out = (float*)d_out;

    const int n = in_sizes[2] / 3;  // N_PTS
    const int nblk = (n + 255) / 256;

    size_t off = 0;
    auto take = [&](size_t bytes) { size_t o = off; off = (off + bytes + 255) & ~(size_t)255; return o; };
    char* ws = (char*)d_ws;
    const size_t cnt_bytes = (size_t)NBINS * REPL * CNT_PAD * 4;       // 2 MB (256-mult.)
    const size_t o_cnt   = take(cnt_bytes);
    const size_t o_ovfc  = take(256);                                   // contiguous after cnt
    const size_t o_slots = take((size_t)NBINS * REPL * CAP * 4);        // 13.6 MB
    const size_t o_ovf   = take((size_t)OVF_CAP * 4);                   // 512 KB
    const size_t needed = off;                                          // ~16.3 MB

    if (ws_size < needed) {
        hipLaunchKernelGGL(direct_kernel, dim3(nblk), dim3(256), 0, stream,
                           coeff, aabb, points, normals, out, n);
        return;
    }

    int* cnt_p   = (int*)(ws + o_cnt);
    int* ovf_cnt = (int*)(ws + o_ovfc);
    int* slots   = (int*)(ws + o_slots);
    int* ovf     = (int*)(ws + o_ovf);

    // zero counters + overflow count in one memset (o_ovfc == o_cnt + cnt_bytes)
    hipMemsetAsync(ws + o_cnt, 0, cnt_bytes + 256, stream);

    hipLaunchKernelGGL(scatter_kernel, dim3(nblk), dim3(256), 0, stream,
                       aabb, points, cnt_p, slots, ovf_cnt, ovf, n);
    hipLaunchKernelGGL(main_kernel, dim3(NBINS), dim3(MAIN_THREADS),
                       TOT_F4 * sizeof(float4), stream,
                       coeff, aabb, points, normals, cnt_p, slots, out);
    hipLaunchKernelGGL(overflow_kernel, dim3(64), dim3(256), 0, stream,
                       coeff, aabb, points, normals, ovf_cnt, ovf, cnt_p, slots, out, n);
}

// Round 3
// 794.751 us; speedup vs baseline: 1.1607x; 1.0422x over previous
//
#include <hip/hip_runtime.h>

// IrradianceVolumes: out[i,c] = relu( sum_j sh_j(normal_i) * trilerp(coeff[...,j,c], point_i) )
// coeff: [128,128,128,16,3] f32 (403 MB), points/normals: [2M,3] f32, out: [2M,3] f32.
//
// Round 7: fix the LDS bank-conflict structure in main_kernel.
//  - Diagnosis (round-6 counters): cell stride in LDS was 48 floats = 192 B == 16 mod
//    32 banks, so every cell starts at bank 0 or 16. Random per-lane cells collapse a
//    wave's 64 ds_read_b128 lanes onto 2 four-bank groups instead of 8 -> ~4x LDS
//    serialization. Predicted extra cycles (~3M wave-reads x ~24cy = 7.2e7) matches
//    measured SQ_LDS_BANK_CONFLICT = 6.2e7 (~100us of main's 281us).
//  - Fix: pad each z-column (9 cells = 108 f4) by +1 f4 -> COL_F4 = 109. Read start
//    group (f4-index mod 8) = (5*col + 4*lz) mod 8: uniform over all 8 groups
//    (5 coprime 8). Reads stay contiguous within a column (z stride still 12 f4).
//    LDS: 77,760 -> 78,480 B; still 2 blocks/CU (81,920 B budget).
//  - overflow_kernel folded into main_kernel (bin-0 block; expected 0 entries):
//    dispatches 4 -> 3.
//  - Capacity-binned one-pass scatter unchanged from round 6 (measured total 828us,
//    main 281us; sort infra replacement already banked ~94us).

constexpr int RES = 128;
constexpr int D2 = 16;
constexpr int CSTRIDE = D2 * 3;       // 48 floats per cell
constexpr int CELL_F4 = CSTRIDE / 4;  // 12 float4 per cell

// bins: x split by 4 (shift 2), y/z by 8 (shift 3)
constexpr int NBX = 32, NBY = 16, NBZ = 16;
constexpr int NBINS = NBX * NBY * NBZ;     // 8192
constexpr int HX = 5, HY = 9, HZ = 9;      // halo cells per axis
constexpr int MAIN_THREADS = 256;

// LDS layout: [col = cx*HY+cy][z-column of 9 cells, padded]
constexpr int SRC_COL_F4 = HZ * CELL_F4;        // 108 f4 of real data per column
constexpr int COL_F4 = SRC_COL_F4 + 1;          // 109: +1 f4 pad -> bank spread
constexpr int NCOL = HX * HY;                   // 45 columns
constexpr int TOT_SRC_F4 = NCOL * SRC_COL_F4;   // 4860 f4 staged from HBM
constexpr int LDS_F4 = NCOL * COL_F4;           // 4905 f4 = 78,480 B
constexpr int LOAD_ITERS = (TOT_SRC_F4 + MAIN_THREADS - 1) / MAIN_THREADS; // 19

constexpr int REPL = 4;          // counter/segment replicas per bin
constexpr int CAP = 104;         // slots per (bin, replica); lambda=64 -> P(ovf)~1e-6
constexpr int CNT_PAD = 16;      // ints per padded counter (64 B line)
constexpr int OVF_CAP = 131072;  // overflow list capacity (512 KB)

__device__ __forceinline__ void grid_coords(const float* aabb, float px, float py, float pz,
                                            int& ix, int& iy, int& iz,
                                            float& fx, float& fy, float& fz)
{
    const float a0 = aabb[0], a1 = aabb[1], a2 = aabb[2];
    const float b0 = aabb[3], b1 = aabb[4], b2 = aabb[5];
    float gx = (px - a0) / (b0 - a0) * (float)(RES - 1);
    float gy = (py - a1) / (b1 - a1) * (float)(RES - 1);
    float gz = (pz - a2) / (b2 - a2) * (float)(RES - 1);
    gx = fminf(fmaxf(gx, 0.0f), (float)(RES - 1));
    gy = fminf(fmaxf(gy, 0.0f), (float)(RES - 1));
    gz = fminf(fmaxf(gz, 0.0f), (float)(RES - 1));
    ix = min((int)floorf(gx), RES - 2);
    iy = min((int)floorf(gy), RES - 2);
    iz = min((int)floorf(gz), RES - 2);
    fx = gx - (float)ix;
    fy = gy - (float)iy;
    fz = gz - (float)iz;
}

__device__ __forceinline__ int bin_of(int ix, int iy, int iz)
{
    return (((ix >> 2) * NBY) + (iy >> 3)) * NBZ + (iz >> 3);
}

__device__ __forceinline__ void sh_basis(float nx, float ny, float nz, float* sh)
{
    const float xx = nx * nx, yy = ny * ny, zz = nz * nz;
    const float xy = nx * ny, yz = ny * nz, xz = nx * nz;
    sh[0]  = 0.28209479177387814f;
    sh[1]  = -0.4886025119029199f * ny;
    sh[2]  = 0.4886025119029199f * nz;
    sh[3]  = -0.4886025119029199f * nx;
    sh[4]  = 1.0925484305920792f * xy;
    sh[5]  = -1.0925484305920792f * yz;
    sh[6]  = 0.31539156525252005f * (2.0f * zz - xx - yy);
    sh[7]  = -1.0925484305920792f * xz;
    sh[8]  = 0.5462742152960396f * (xx - yy);
    sh[9]  = -0.5900435899266435f * ny * (3.0f * xx - yy);
    sh[10] = 2.890611442640554f * xy * nz;
    sh[11] = -0.4570457994644658f * ny * (4.0f * zz - xx - yy);
    sh[12] = 0.3731763325901154f * nz * (2.0f * zz - 3.0f * xx - 3.0f * yy);
    sh[13] = -0.4570457994644658f * nx * (4.0f * zz - xx - yy);
    sh[14] = 1.445305721320277f * nz * (xx - yy);
    sh[15] = -0.5900435899266435f * nx * (xx - 3.0f * yy);
}

// Fully-direct per-point evaluation from global memory (fallback / overflow path).
__device__ void compute_point_global(
    const float* __restrict__ coeff,
    const float* __restrict__ aabb,
    const float* __restrict__ points,
    const float* __restrict__ normals,
    float* __restrict__ out, int i)
{
    const float px = points[3 * i + 0], py = points[3 * i + 1], pz = points[3 * i + 2];
    const float nx = normals[3 * i + 0], ny = normals[3 * i + 1], nz = normals[3 * i + 2];
    int ix, iy, iz; float fx, fy, fz;
    grid_coords(aabb, px, py, pz, ix, iy, iz, fx, fy, fz);
    float sh[D2];
    sh_basis(nx, ny, nz, sh);
    const float wz0 = 1.0f - fz, wz1 = fz;
    float acc0 = 0.0f, acc1 = 0.0f, acc2 = 0.0f;
#pragma unroll
    for (int dx = 0; dx < 2; ++dx) {
        const float wx = dx ? fx : 1.0f - fx;
#pragma unroll
        for (int dy = 0; dy < 2; ++dy) {
            const float wxy = wx * (dy ? fy : 1.0f - fy);
            const int cell = (((ix + dx) * RES + (iy + dy)) * RES + iz) * CSTRIDE;
            const float4* __restrict__ cp = (const float4*)(coeff + cell);
            union { float4 q[24]; float v[96]; } u;
#pragma unroll
            for (int kk = 0; kk < 24; ++kk) u.q[kk] = cp[kk];
            float s00 = 0.f, s01 = 0.f, s02 = 0.f;
            float s10 = 0.f, s11 = 0.f, s12 = 0.f;
#pragma unroll
            for (int j = 0; j < D2; ++j) {
                const float s = sh[j];
                s00 = fmaf(s, u.v[3 * j + 0], s00);
                s01 = fmaf(s, u.v[3 * j + 1], s01);
                s02 = fmaf(s, u.v[3 * j + 2], s02);
                s10 = fmaf(s, u.v[48 + 3 * j + 0], s10);
                s11 = fmaf(s, u.v[48 + 3 * j + 1], s11);
                s12 = fmaf(s, u.v[48 + 3 * j + 2], s12);
            }
            const float w0 = wxy * wz0, w1 = wxy * wz1;
            acc0 = fmaf(w0, s00, fmaf(w1, s10, acc0));
            acc1 = fmaf(w0, s01, fmaf(w1, s11, acc1));
            acc2 = fmaf(w0, s02, fmaf(w1, s12, acc2));
        }
    }
    out[3 * i + 0] = fmaxf(acc0, 0.0f);
    out[3 * i + 1] = fmaxf(acc1, 0.0f);
    out[3 * i + 2] = fmaxf(acc2, 0.0f);
}

// ---------------- pass 1: capacity-binned scatter ----------------
__global__ __launch_bounds__(256) void scatter_kernel(
    const float* __restrict__ aabb,
    const float* __restrict__ points,
    int* __restrict__ cnt_p,      // NBINS * REPL * CNT_PAD, pre-zeroed
    int* __restrict__ slots,      // NBINS * REPL * CAP
    int* __restrict__ ovf_cnt,    // [0]=count, [1]=dropped flag; pre-zeroed
    int* __restrict__ ovf,        // OVF_CAP
    int n)
{
    const int i = blockIdx.x * blockDim.x + threadIdx.x;
    if (i >= n) return;
    int ix, iy, iz; float fx, fy, fz;
    grid_coords(aabb, points[3 * i + 0], points[3 * i + 1], points[3 * i + 2],
                ix, iy, iz, fx, fy, fz);
    const int bin = bin_of(ix, iy, iz);
    const int rep = (i >> 6) & (REPL - 1);   // wave-uniform replica choice
    const int g = bin * REPL + rep;
    const int pos = atomicAdd(&cnt_p[g * CNT_PAD], 1);
    if (pos < CAP) {
        slots[g * CAP + pos] = i;
    } else {
        const int o = atomicAdd(&ovf_cnt[0], 1);
        if (o < OVF_CAP) ovf[o] = i;
        else ovf_cnt[1] = 1;  // adversarial input: signal full re-sweep
    }
}

// ---------------- pass 2: one block per bin, LDS-staged gather ----------------
// Bin-0 block additionally drains the overflow list (expected empty).
__global__ __launch_bounds__(MAIN_THREADS) void main_kernel(
    const float* __restrict__ coeff,
    const float* __restrict__ aabb,
    const float* __restrict__ points,
    const float* __restrict__ normals,
    const int* __restrict__ cnt_p,
    const int* __restrict__ slots,
    const int* __restrict__ ovf_cnt,
    const int* __restrict__ ovf,
    float* __restrict__ out,
    int n)
{
    extern __shared__ char smem[];
    float4* lds4 = (float4*)smem;

    const int bin = blockIdx.x;
    const int tid = threadIdx.x;
    const bool ovf_block = (bin == 0);

    const int c0 = min(cnt_p[(bin * REPL + 0) * CNT_PAD], CAP);
    const int c1 = min(cnt_p[(bin * REPL + 1) * CNT_PAD], CAP);
    const int c2 = min(cnt_p[(bin * REPL + 2) * CNT_PAD], CAP);
    const int c3 = min(cnt_p[(bin * REPL + 3) * CNT_PAD], CAP);
    const int tot = c0 + c1 + c2 + c3;
    if (tot == 0 && !ovf_block) return;

    if (tot > 0) {
        const int bx = bin / (NBY * NBZ);
        const int by = (bin / NBZ) % NBY;
        const int bz = bin % NBZ;
        const int x0 = bx << 2;
        const int y0 = by << 3;
        const int z0 = bz << 3;

        const float4* __restrict__ coeff4 = (const float4*)coeff;

        // ---- stage 5x9x9-cell halo into LDS, z-column-padded layout ----
        // dest f4 index = col*COL_F4 + rem, col = cx*HY+cy, rem = cz*CELL_F4+kk
#pragma unroll
        for (int k = 0; k < LOAD_ITERS; ++k) {
            const int u = tid + k * MAIN_THREADS;
            if (u < TOT_SRC_F4) {
                int col = u / SRC_COL_F4;                // /108
                int rem = u - col * SRC_COL_F4;
                int cx = col / HY;                       // /9
                int cy = col - cx * HY;
                int cz = rem / CELL_F4;                  // /12
                int kk = rem - cz * CELL_F4;
                int xg = min(x0 + cx, RES - 1);
                int yg = min(y0 + cy, RES - 1);
                int zg = min(z0 + cz, RES - 1);
                lds4[col * COL_F4 + rem] = coeff4[((xg * RES + yg) * RES + zg) * CELL_F4 + kk];
            }
        }
        __syncthreads();

        // ---- compute this bin's points from LDS ----
        for (int t = tid; t < tot; t += MAIN_THREADS) {
            int k = t, r = 0;
            if (k >= c0) { k -= c0; r = 1;
                if (k >= c1) { k -= c1; r = 2;
                    if (k >= c2) { k -= c2; r = 3; } } }
            const int i = slots[(bin * REPL + r) * CAP + k];

            const float px = points[3 * i + 0];
            const float py = points[3 * i + 1];
            const float pz = points[3 * i + 2];
            const float nx = normals[3 * i + 0];
            const float ny = normals[3 * i + 1];
            const float nz = normals[3 * i + 2];

            int ix, iy, iz; float fx, fy, fz;
            grid_coords(aabb, px, py, pz, ix, iy, iz, fx, fy, fz);
            const int lx = ix - x0, ly = iy - y0, lz = iz - z0;

            float sh[D2];
            sh_basis(nx, ny, nz, sh);

            const float wz0 = 1.0f - fz, wz1 = fz;
            float acc0 = 0.0f, acc1 = 0.0f, acc2 = 0.0f;

#pragma unroll
            for (int dx = 0; dx < 2; ++dx) {
                const float wx = dx ? fx : 1.0f - fx;
#pragma unroll
                for (int dy = 0; dy < 2; ++dy) {
                    const float wxy = wx * (dy ? fy : 1.0f - fy);
                    // contiguous 24 f4 within one padded z-column (covers lz, lz+1)
                    const int lbase = ((lx + dx) * HY + (ly + dy)) * COL_F4 + lz * CELL_F4;
                    union { float4 q[24]; float v[96]; } u;
#pragma unroll
                    for (int kk = 0; kk < 24; ++kk) u.q[kk] = lds4[lbase + kk];

                    float s00 = 0.f, s01 = 0.f, s02 = 0.f;
                    float s10 = 0.f, s11 = 0.f, s12 = 0.f;
#pragma unroll
                    for (int j = 0; j < D2; ++j) {
                        const float s = sh[j];
                        s00 = fmaf(s, u.v[3 * j + 0], s00);
                        s01 = fmaf(s, u.v[3 * j + 1], s01);
                        s02 = fmaf(s, u.v[3 * j + 2], s02);
                        s10 = fmaf(s, u.v[48 + 3 * j + 0], s10);
                        s11 = fmaf(s, u.v[48 + 3 * j + 1], s11);
                        s12 = fmaf(s, u.v[48 + 3 * j + 2], s12);
                    }
                    const float w0 = wxy * wz0, w1 = wxy * wz1;
                    acc0 = fmaf(w0, s00, fmaf(w1, s10, acc0));
                    acc1 = fmaf(w0, s01, fmaf(w1, s11, acc1));
                    acc2 = fmaf(w0, s02, fmaf(w1, s12, acc2));
                }
            }

            out[3 * i + 0] = fmaxf(acc0, 0.0f);
            out[3 * i + 1] = fmaxf(acc1, 0.0f);
            out[3 * i + 2] = fmaxf(acc2, 0.0f);
        }
    }

    // ---- overflow drain (bin-0 block only; expected 0 entries) ----
    if (ovf_block) {
        const int m = min(ovf_cnt[0], OVF_CAP);
        for (int t = tid; t < m; t += MAIN_THREADS)
            compute_point_global(coeff, aabb, points, normals, out, ovf[t]);

        // Adversarial-input path (ovf list overflowed): re-derive placement per point.
        if (ovf_cnt[1]) {
            for (int i = tid; i < n; i += MAIN_THREADS) {
                int ix, iy, iz; float fx, fy, fz;
                grid_coords(aabb, points[3 * i + 0], points[3 * i + 1], points[3 * i + 2],
                            ix, iy, iz, fx, fy, fz);
                const int g = bin_of(ix, iy, iz) * REPL + ((i >> 6) & (REPL - 1));
                const int c = min(cnt_p[g * CNT_PAD], CAP);
                bool placed = false;
                for (int k = 0; k < c && !placed; ++k) placed = (slots[g * CAP + k] == i);
                for (int k = 0; k < m && !placed; ++k)  placed = (ovf[k] == i);
                if (!placed) compute_point_global(coeff, aabb, points, normals, out, i);
            }
        }
    }
}

// ---------------- fallback: direct, unsorted ----------------
__global__ __launch_bounds__(256) void direct_kernel(
    const float* __restrict__ coeff,
    const float* __restrict__ aabb,
    const float* __restrict__ points,
    const float* __restrict__ normals,
    float* __restrict__ out,
    int n)
{
    const int i = blockIdx.x * blockDim.x + threadIdx.x;
    if (i >= n) return;
    compute_point_global(coeff, aabb, points, normals, out, i);
}

extern "C" void kernel_launch(void* const* d_in, const int* in_sizes, int n_in,
                              void* d_out, int out_size, void* d_ws, size_t ws_size,
                              hipStream_t stream) {
    const float* coeff   = (const float*)d_in[0];
    const float* aabb    = (const float*)d_in[1];
    const float* points  = (const float*)d_in[2];
    const float* normals = (const float*)d_in[3];
    float* out = (float*)d_out;

    const int n = in_sizes[2] / 3;  // N_PTS
    const int nblk = (n + 255) / 256;

    size_t off = 0;
    auto take = [&](size_t bytes) { size_t o = off; off = (off + bytes + 255) & ~(size_t)255; return o; };
    char* ws = (char*)d_ws;
    const size_t cnt_bytes = (size_t)NBINS * REPL * CNT_PAD * 4;       // 2 MB (256-mult.)
    const size_t o_cnt   = take(cnt_bytes);
    const size_t o_ovfc  = take(256);                                   // contiguous after cnt
    const size_t o_slots = take((size_t)NBINS * REPL * CAP * 4);        // 13.6 MB
    const size_t o_ovf   = take((size_t)OVF_CAP * 4);                   // 512 KB
    const size_t needed = off;                                          // ~16.3 MB

    if (ws_size < needed) {
        hipLaunchKernelGGL(direct_kernel, dim3(nblk), dim3(256), 0, stream,
                           coeff, aabb, points, normals, out, n);
        return;
    }

    int* cnt_p   = (int*)(ws + o_cnt);
    int* ovf_cnt = (int*)(ws + o_ovfc);
    int* slots   = (int*)(ws + o_slots);
    int* ovf     = (int*)(ws + o_ovf);

    // zero counters + overflow count in one memset (o_ovfc == o_cnt + cnt_bytes)
    hipMemsetAsync(ws + o_cnt, 0, cnt_bytes + 256, stream);

    hipLaunchKernelGGL(scatter_kernel, dim3(nblk), dim3(256), 0, stream,
                       aabb, points, cnt_p, slots, ovf_cnt, ovf, n);
    hipLaunchKernelGGL(main_kernel, dim3(NBINS), dim3(MAIN_THREADS),
                       LDS_F4 * sizeof(float4), stream,
                       coeff, aabb, points, normals, cnt_p, slots, ovf_cnt, ovf, out, n);
}

// Round 4
// 753.891 us; speedup vs baseline: 1.2236x; 1.0542x over previous
//
#include <hip/hip_runtime.h>

// IrradianceVolumes: out[i,c] = relu( sum_j sh_j(normal_i) * trilerp(coeff[...,j,c], point_i) )
// coeff: [128,128,128,16,3] f32 (403 MB), points/normals: [2M,3] f32, out: [2M,3] f32.
//
// Round 8:
//  - rocclr fillBufferAligned measured at 8 GB/s (2 MB memset = 256 us, counter-
//    confirmed). Replaced with our own grid-stride zero_kernel (~3 us).
//  - By subtraction (795 = fill ~250 + scatter ~250 + main 255), scatter is also
//    ~250 us. Scatter already RMWs one 64-B line per point for its 4-B slot write,
//    so storing the full 32-B point record (px,py,pz,nx,ny,nz,bitcast(i)) is free
//    at the line level. main_kernel then reads slots CONTIGUOUSLY and drops the
//    sidx->points/normals random gather (~250 MB of its 513 MB FETCH, plus a
//    dependent-load chain at 20% occupancy).
//  - Data-slots path needs ~112 MB workspace; gated on ws_size with the proven
//    round-7 index path (16.3 MB) as fallback, direct kernel as last resort.
//  - main keeps round-7's z-column-padded LDS layout (conflicts 6.2e7 -> 2.4e7).

constexpr int RES = 128;
constexpr int D2 = 16;
constexpr int CSTRIDE = D2 * 3;       // 48 floats per cell
constexpr int CELL_F4 = CSTRIDE / 4;  // 12 float4 per cell

// bins: x split by 4 (shift 2), y/z by 8 (shift 3)
constexpr int NBX = 32, NBY = 16, NBZ = 16;
constexpr int NBINS = NBX * NBY * NBZ;     // 8192
constexpr int HX = 5, HY = 9, HZ = 9;      // halo cells per axis
constexpr int MAIN_THREADS = 256;

// LDS layout: [col = cx*HY+cy][z-column of 9 cells, padded +1 f4]
constexpr int SRC_COL_F4 = HZ * CELL_F4;        // 108 f4 real data per column
constexpr int COL_F4 = SRC_COL_F4 + 1;          // 109 -> bank-group spread (5 coprime 8)
constexpr int NCOL = HX * HY;                   // 45 columns
constexpr int TOT_SRC_F4 = NCOL * SRC_COL_F4;   // 4860 f4 staged from HBM
constexpr int LDS_F4 = NCOL * COL_F4;           // 4905 f4 = 78,480 B
constexpr int LOAD_ITERS = (TOT_SRC_F4 + MAIN_THREADS - 1) / MAIN_THREADS; // 19

constexpr int REPL = 4;          // counter/segment replicas per bin
constexpr int CAP = 104;         // slots per (bin, replica); lambda=64 -> P(ovf)~1e-6
constexpr int CNT_PAD = 16;      // ints per padded counter (64 B line)
constexpr int OVF_CAP = 131072;  // overflow list capacity (512 KB)

__device__ __forceinline__ void grid_coords(const float* aabb, float px, float py, float pz,
                                            int& ix, int& iy, int& iz,
                                            float& fx, float& fy, float& fz)
{
    const float a0 = aabb[0], a1 = aabb[1], a2 = aabb[2];
    const float b0 = aabb[3], b1 = aabb[4], b2 = aabb[5];
    float gx = (px - a0) / (b0 - a0) * (float)(RES - 1);
    float gy = (py - a1) / (b1 - a1) * (float)(RES - 1);
    float gz = (pz - a2) / (b2 - a2) * (float)(RES - 1);
    gx = fminf(fmaxf(gx, 0.0f), (float)(RES - 1));
    gy = fminf(fmaxf(gy, 0.0f), (float)(RES - 1));
    gz = fminf(fmaxf(gz, 0.0f), (float)(RES - 1));
    ix = min((int)floorf(gx), RES - 2);
    iy = min((int)floorf(gy), RES - 2);
    iz = min((int)floorf(gz), RES - 2);
    fx = gx - (float)ix;
    fy = gy - (float)iy;
    fz = gz - (float)iz;
}

__device__ __forceinline__ int bin_of(int ix, int iy, int iz)
{
    return (((ix >> 2) * NBY) + (iy >> 3)) * NBZ + (iz >> 3);
}

__device__ __forceinline__ void sh_basis(float nx, float ny, float nz, float* sh)
{
    const float xx = nx * nx, yy = ny * ny, zz = nz * nz;
    const float xy = nx * ny, yz = ny * nz, xz = nx * nz;
    sh[0]  = 0.28209479177387814f;
    sh[1]  = -0.4886025119029199f * ny;
    sh[2]  = 0.4886025119029199f * nz;
    sh[3]  = -0.4886025119029199f * nx;
    sh[4]  = 1.0925484305920792f * xy;
    sh[5]  = -1.0925484305920792f * yz;
    sh[6]  = 0.31539156525252005f * (2.0f * zz - xx - yy);
    sh[7]  = -1.0925484305920792f * xz;
    sh[8]  = 0.5462742152960396f * (xx - yy);
    sh[9]  = -0.5900435899266435f * ny * (3.0f * xx - yy);
    sh[10] = 2.890611442640554f * xy * nz;
    sh[11] = -0.4570457994644658f * ny * (4.0f * zz - xx - yy);
    sh[12] = 0.3731763325901154f * nz * (2.0f * zz - 3.0f * xx - 3.0f * yy);
    sh[13] = -0.4570457994644658f * nx * (4.0f * zz - xx - yy);
    sh[14] = 1.445305721320277f * nz * (xx - yy);
    sh[15] = -0.5900435899266435f * nx * (xx - 3.0f * yy);
}

// Shared inner math: given point/normal + local LDS coords, accumulate and store.
__device__ __forceinline__ void eval_from_lds(
    const float4* __restrict__ lds4, const float* __restrict__ aabb,
    float px, float py, float pz, float nx, float ny, float nz,
    int x0, int y0, int z0, int i, float* __restrict__ out)
{
    int ix, iy, iz; float fx, fy, fz;
    grid_coords(aabb, px, py, pz, ix, iy, iz, fx, fy, fz);
    const int lx = ix - x0, ly = iy - y0, lz = iz - z0;

    float sh[D2];
    sh_basis(nx, ny, nz, sh);

    const float wz0 = 1.0f - fz, wz1 = fz;
    float acc0 = 0.0f, acc1 = 0.0f, acc2 = 0.0f;

#pragma unroll
    for (int dx = 0; dx < 2; ++dx) {
        const float wx = dx ? fx : 1.0f - fx;
#pragma unroll
        for (int dy = 0; dy < 2; ++dy) {
            const float wxy = wx * (dy ? fy : 1.0f - fy);
            // contiguous 24 f4 within one padded z-column (covers lz, lz+1)
            const int lbase = ((lx + dx) * HY + (ly + dy)) * COL_F4 + lz * CELL_F4;
            union { float4 q[24]; float v[96]; } u;
#pragma unroll
            for (int kk = 0; kk < 24; ++kk) u.q[kk] = lds4[lbase + kk];

            float s00 = 0.f, s01 = 0.f, s02 = 0.f;
            float s10 = 0.f, s11 = 0.f, s12 = 0.f;
#pragma unroll
            for (int j = 0; j < D2; ++j) {
                const float s = sh[j];
                s00 = fmaf(s, u.v[3 * j + 0], s00);
                s01 = fmaf(s, u.v[3 * j + 1], s01);
                s02 = fmaf(s, u.v[3 * j + 2], s02);
                s10 = fmaf(s, u.v[48 + 3 * j + 0], s10);
                s11 = fmaf(s, u.v[48 + 3 * j + 1], s11);
                s12 = fmaf(s, u.v[48 + 3 * j + 2], s12);
            }
            const float w0 = wxy * wz0, w1 = wxy * wz1;
            acc0 = fmaf(w0, s00, fmaf(w1, s10, acc0));
            acc1 = fmaf(w0, s01, fmaf(w1, s11, acc1));
            acc2 = fmaf(w0, s02, fmaf(w1, s12, acc2));
        }
    }

    out[3 * i + 0] = fmaxf(acc0, 0.0f);
    out[3 * i + 1] = fmaxf(acc1, 0.0f);
    out[3 * i + 2] = fmaxf(acc2, 0.0f);
}

// Fully-direct per-point evaluation from global memory (fallback / overflow path).
__device__ void compute_point_global(
    const float* __restrict__ coeff,
    const float* __restrict__ aabb,
    const float* __restrict__ points,
    const float* __restrict__ normals,
    float* __restrict__ out, int i)
{
    const float px = points[3 * i + 0], py = points[3 * i + 1], pz = points[3 * i + 2];
    const float nx = normals[3 * i + 0], ny = normals[3 * i + 1], nz = normals[3 * i + 2];
    int ix, iy, iz; float fx, fy, fz;
    grid_coords(aabb, px, py, pz, ix, iy, iz, fx, fy, fz);
    float sh[D2];
    sh_basis(nx, ny, nz, sh);
    const float wz0 = 1.0f - fz, wz1 = fz;
    float acc0 = 0.0f, acc1 = 0.0f, acc2 = 0.0f;
#pragma unroll
    for (int dx = 0; dx < 2; ++dx) {
        const float wx = dx ? fx : 1.0f - fx;
#pragma unroll
        for (int dy = 0; dy < 2; ++dy) {
            const float wxy = wx * (dy ? fy : 1.0f - fy);
            const int cell = (((ix + dx) * RES + (iy + dy)) * RES + iz) * CSTRIDE;
            const float4* __restrict__ cp = (const float4*)(coeff + cell);
            union { float4 q[24]; float v[96]; } u;
#pragma unroll
            for (int kk = 0; kk < 24; ++kk) u.q[kk] = cp[kk];
            float s00 = 0.f, s01 = 0.f, s02 = 0.f;
            float s10 = 0.f, s11 = 0.f, s12 = 0.f;
#pragma unroll
            for (int j = 0; j < D2; ++j) {
                const float s = sh[j];
                s00 = fmaf(s, u.v[3 * j + 0], s00);
                s01 = fmaf(s, u.v[3 * j + 1], s01);
                s02 = fmaf(s, u.v[3 * j + 2], s02);
                s10 = fmaf(s, u.v[48 + 3 * j + 0], s10);
                s11 = fmaf(s, u.v[48 + 3 * j + 1], s11);
                s12 = fmaf(s, u.v[48 + 3 * j + 2], s12);
            }
            const float w0 = wxy * wz0, w1 = wxy * wz1;
            acc0 = fmaf(w0, s00, fmaf(w1, s10, acc0));
            acc1 = fmaf(w0, s01, fmaf(w1, s11, acc1));
            acc2 = fmaf(w0, s02, fmaf(w1, s12, acc2));
        }
    }
    out[3 * i + 0] = fmaxf(acc0, 0.0f);
    out[3 * i + 1] = fmaxf(acc1, 0.0f);
    out[3 * i + 2] = fmaxf(acc2, 0.0f);
}

// ---------------- pass 0: zero counters (replaces 8 GB/s rocclr fill) ----------------
__global__ __launch_bounds__(256) void zero_kernel(uint4* __restrict__ p, int n16)
{
    const int i = blockIdx.x * blockDim.x + threadIdx.x;
    if (i < n16) p[i] = make_uint4(0u, 0u, 0u, 0u);
}

// ---------------- pass 1a: capacity-binned scatter, DATA payload (preferred) -------
__global__ __launch_bounds__(256) void scatter_data_kernel(
    const float* __restrict__ aabb,
    const float* __restrict__ points,
    const float* __restrict__ normals,
    int* __restrict__ cnt_p,       // NBINS * REPL * CNT_PAD, pre-zeroed
    float4* __restrict__ slots8,   // NBINS * REPL * CAP records x 2 float4
    int* __restrict__ ovf_cnt,     // [0]=count, [1]=dropped flag; pre-zeroed
    int* __restrict__ ovf,         // OVF_CAP (indices)
    int n)
{
    const int i = blockIdx.x * blockDim.x + threadIdx.x;
    if (i >= n) return;
    const float px = points[3 * i + 0], py = points[3 * i + 1], pz = points[3 * i + 2];
    int ix, iy, iz; float fx, fy, fz;
    grid_coords(aabb, px, py, pz, ix, iy, iz, fx, fy, fz);
    const int bin = bin_of(ix, iy, iz);
    const int rep = (i >> 6) & (REPL - 1);   // wave-uniform replica choice
    const int g = bin * REPL + rep;
    const int pos = atomicAdd(&cnt_p[g * CNT_PAD], 1);
    if (pos < CAP) {
        const float nx = normals[3 * i + 0], ny = normals[3 * i + 1], nz = normals[3 * i + 2];
        const int rec = (g * CAP + pos) * 2;
        slots8[rec + 0] = make_float4(px, py, pz, nx);
        slots8[rec + 1] = make_float4(ny, nz, __int_as_float(i), 0.0f);
    } else {
        const int o = atomicAdd(&ovf_cnt[0], 1);
        if (o < OVF_CAP) ovf[o] = i;
        else ovf_cnt[1] = 1;  // adversarial input: signal full re-sweep
    }
}

// ---------------- pass 1b: capacity-binned scatter, INDEX payload (fallback) -------
__global__ __launch_bounds__(256) void scatter_idx_kernel(
    const float* __restrict__ aabb,
    const float* __restrict__ points,
    int* __restrict__ cnt_p,
    int* __restrict__ slots,
    int* __restrict__ ovf_cnt,
    int* __restrict__ ovf,
    int n)
{
    const int i = blockIdx.x * blockDim.x + threadIdx.x;
    if (i >= n) return;
    int ix, iy, iz; float fx, fy, fz;
    grid_coords(aabb, points[3 * i + 0], points[3 * i + 1], points[3 * i + 2],
                ix, iy, iz, fx, fy, fz);
    const int bin = bin_of(ix, iy, iz);
    const int rep = (i >> 6) & (REPL - 1);
    const int g = bin * REPL + rep;
    const int pos = atomicAdd(&cnt_p[g * CNT_PAD], 1);
    if (pos < CAP) {
        slots[g * CAP + pos] = i;
    } else {
        const int o = atomicAdd(&ovf_cnt[0], 1);
        if (o < OVF_CAP) ovf[o] = i;
        else ovf_cnt[1] = 1;
    }
}

// ---------------- staging helper (shared by both mains) ----------------
__device__ __forceinline__ void stage_halo(
    float4* __restrict__ lds4, const float4* __restrict__ coeff4,
    int x0, int y0, int z0, int tid)
{
#pragma unroll
    for (int k = 0; k < LOAD_ITERS; ++k) {
        const int u = tid + k * MAIN_THREADS;
        if (u < TOT_SRC_F4) {
            int col = u / SRC_COL_F4;                // /108
            int rem = u - col * SRC_COL_F4;
            int cx = col / HY;                       // /9
            int cy = col - cx * HY;
            int cz = rem / CELL_F4;                  // /12
            int kk = rem - cz * CELL_F4;
            int xg = min(x0 + cx, RES - 1);
            int yg = min(y0 + cy, RES - 1);
            int zg = min(z0 + cz, RES - 1);
            lds4[col * COL_F4 + rem] = coeff4[((xg * RES + yg) * RES + zg) * CELL_F4 + kk];
        }
    }
}

// ---------------- pass 2a: main, DATA slots (contiguous record reads) ----------------
__global__ __launch_bounds__(MAIN_THREADS) void main_data_kernel(
    const float* __restrict__ coeff,
    const float* __restrict__ aabb,
    const float* __restrict__ points,
    const float* __restrict__ normals,
    const int* __restrict__ cnt_p,
    const float4* __restrict__ slots8,
    const int* __restrict__ ovf_cnt,
    const int* __restrict__ ovf,
    float* __restrict__ out,
    int n)
{
    extern __shared__ char smem[];
    float4* lds4 = (float4*)smem;

    const int bin = blockIdx.x;
    const int tid = threadIdx.x;
    const bool ovf_block = (bin == 0);

    const int c0 = min(cnt_p[(bin * REPL + 0) * CNT_PAD], CAP);
    const int c1 = min(cnt_p[(bin * REPL + 1) * CNT_PAD], CAP);
    const int c2 = min(cnt_p[(bin * REPL + 2) * CNT_PAD], CAP);
    const int c3 = min(cnt_p[(bin * REPL + 3) * CNT_PAD], CAP);
    const int tot = c0 + c1 + c2 + c3;
    if (tot == 0 && !ovf_block) return;

    if (tot > 0) {
        const int bx = bin / (NBY * NBZ);
        const int by = (bin / NBZ) % NBY;
        const int bz = bin % NBZ;
        const int x0 = bx << 2, y0 = by << 3, z0 = bz << 3;

        stage_halo(lds4, (const float4*)coeff, x0, y0, z0, tid);
        __syncthreads();

        for (int t = tid; t < tot; t += MAIN_THREADS) {
            int k = t, r = 0;
            if (k >= c0) { k -= c0; r = 1;
                if (k >= c1) { k -= c1; r = 2;
                    if (k >= c2) { k -= c2; r = 3; } } }
            const int rec = ((bin * REPL + r) * CAP + k) * 2;
            const float4 lo = slots8[rec + 0];
            const float4 hi = slots8[rec + 1];
            const int i = __float_as_int(hi.z);
            eval_from_lds(lds4, aabb, lo.x, lo.y, lo.z, lo.w, hi.x, hi.y,
                          x0, y0, z0, i, out);
        }
    }

    if (ovf_block) {
        const int m = min(ovf_cnt[0], OVF_CAP);
        for (int t = tid; t < m; t += MAIN_THREADS)
            compute_point_global(coeff, aabb, points, normals, out, ovf[t]);

        if (ovf_cnt[1]) {  // adversarial: re-derive placement per point
            for (int i = tid; i < n; i += MAIN_THREADS) {
                int ix, iy, iz; float fx, fy, fz;
                grid_coords(aabb, points[3 * i + 0], points[3 * i + 1], points[3 * i + 2],
                            ix, iy, iz, fx, fy, fz);
                const int g = bin_of(ix, iy, iz) * REPL + ((i >> 6) & (REPL - 1));
                const int c = min(cnt_p[g * CNT_PAD], CAP);
                bool placed = false;
                for (int k = 0; k < c && !placed; ++k)
                    placed = (__float_as_int(slots8[(g * CAP + k) * 2 + 1].z) == i);
                for (int k = 0; k < m && !placed; ++k) placed = (ovf[k] == i);
                if (!placed) compute_point_global(coeff, aabb, points, normals, out, i);
            }
        }
    }
}

// ---------------- pass 2b: main, INDEX slots (round-7 fallback) ----------------
__global__ __launch_bounds__(MAIN_THREADS) void main_idx_kernel(
    const float* __restrict__ coeff,
    const float* __restrict__ aabb,
    const float* __restrict__ points,
    const float* __restrict__ normals,
    const int* __restrict__ cnt_p,
    const int* __restrict__ slots,
    const int* __restrict__ ovf_cnt,
    const int* __restrict__ ovf,
    float* __restrict__ out,
    int n)
{
    extern __shared__ char smem[];
    float4* lds4 = (float4*)smem;

    const int bin = blockIdx.x;
    const int tid = threadIdx.x;
    const bool ovf_block = (bin == 0);

    const int c0 = min(cnt_p[(bin * REPL + 0) * CNT_PAD], CAP);
    const int c1 = min(cnt_p[(bin * REPL + 1) * CNT_PAD], CAP);
    const int c2 = min(cnt_p[(bin * REPL + 2) * CNT_PAD], CAP);
    const int c3 = min(cnt_p[(bin * REPL + 3) * CNT_PAD], CAP);
    const int tot = c0 + c1 + c2 + c3;
    if (tot == 0 && !ovf_block) return;

    if (tot > 0) {
        const int bx = bin / (NBY * NBZ);
        const int by = (bin / NBZ) % NBY;
        const int bz = bin % NBZ;
        const int x0 = bx << 2, y0 = by << 3, z0 = bz << 3;

        stage_halo(lds4, (const float4*)coeff, x0, y0, z0, tid);
        __syncthreads();

        for (int t = tid; t < tot; t += MAIN_THREADS) {
            int k = t, r = 0;
            if (k >= c0) { k -= c0; r = 1;
                if (k >= c1) { k -= c1; r = 2;
                    if (k >= c2) { k -= c2; r = 3; } } }
            const int i = slots[(bin * REPL + r) * CAP + k];
            const float px = points[3 * i + 0];
            const float py = points[3 * i + 1];
            const float pz = points[3 * i + 2];
            const float nx = normals[3 * i + 0];
            const float ny = normals[3 * i + 1];
            const float nz = normals[3 * i + 2];
            eval_from_lds(lds4, aabb, px, py, pz, nx, ny, nz, x0, y0, z0, i, out);
        }
    }

    if (ovf_block) {
        const int m = min(ovf_cnt[0], OVF_CAP);
        for (int t = tid; t < m; t += MAIN_THREADS)
            compute_point_global(coeff, aabb, points, normals, out, ovf[t]);

        if (ovf_cnt[1]) {
            for (int i = tid; i < n; i += MAIN_THREADS) {
                int ix, iy, iz; float fx, fy, fz;
                grid_coords(aabb, points[3 * i + 0], points[3 * i + 1], points[3 * i + 2],
                            ix, iy, iz, fx, fy, fz);
                const int g = bin_of(ix, iy, iz) * REPL + ((i >> 6) & (REPL - 1));
                const int c = min(cnt_p[g * CNT_PAD], CAP);
                bool placed = false;
                for (int k = 0; k < c && !placed; ++k) placed = (slots[g * CAP + k] == i);
                for (int k = 0; k < m && !placed; ++k)  placed = (ovf[k] == i);
                if (!placed) compute_point_global(coeff, aabb, points, normals, out, i);
            }
        }
    }
}

// ---------------- fallback: direct, unsorted ----------------
__global__ __launch_bounds__(256) void direct_kernel(
    const float* __restrict__ coeff,
    const float* __restrict__ aabb,
    const float* __restrict__ points,
    const float* __restrict__ normals,
    float* __restrict__ out,
    int n)
{
    const int i = blockIdx.x * blockDim.x + threadIdx.x;
    if (i >= n) return;
    compute_point_global(coeff, aabb, points, normals, out, i);
}

extern "C" void kernel_launch(void* const* d_in, const int* in_sizes, int n_in,
                              void* d_out, int out_size, void* d_ws, size_t ws_size,
                              hipStream_t stream) {
    const float* coeff   = (const float*)d_in[0];
    const float* aabb    = (const float*)d_in[1];
    const float* points  = (const float*)d_in[2];
    const float* normals = (const float*)d_in[3];
    float* out = (float*)d_out;

    const int n = in_sizes[2] / 3;  // N_PTS
    const int nblk = (n + 255) / 256;
    char* ws = (char*)d_ws;

    const size_t cnt_bytes = (size_t)NBINS * REPL * CNT_PAD * 4;   // 2 MB, 256-mult.
    const size_t ovfc_bytes = 256;
    const size_t ovf_bytes = (size_t)OVF_CAP * 4;                  // 512 KB
    const size_t slots_data_bytes = (size_t)NBINS * REPL * CAP * 32; // 109 MB
    const size_t slots_idx_bytes  = (size_t)NBINS * REPL * CAP * 4;  // 13.6 MB

    const size_t need_data = cnt_bytes + ovfc_bytes + ovf_bytes + slots_data_bytes;
    const size_t need_idx  = cnt_bytes + ovfc_bytes + ovf_bytes + slots_idx_bytes;

    if (ws_size < need_idx) {
        hipLaunchKernelGGL(direct_kernel, dim3(nblk), dim3(256), 0, stream,
                           coeff, aabb, points, normals, out, n);
        return;
    }

    // layout: [cnt | ovf_cnt | ovf | slots]  (cnt+ovfc contiguous for one zero pass)
    int* cnt_p   = (int*)(ws);
    int* ovf_cnt = (int*)(ws + cnt_bytes);
    int* ovf     = (int*)(ws + cnt_bytes + ovfc_bytes);
    char* slots_base = ws + cnt_bytes + ovfc_bytes + ovf_bytes;

    const int zero16 = (int)((cnt_bytes + ovfc_bytes) / 16);
    hipLaunchKernelGGL(zero_kernel, dim3((zero16 + 255) / 256), dim3(256), 0, stream,
                       (uint4*)ws, zero16);

    if (ws_size >= need_data) {
        float4* slots8 = (float4*)slots_base;
        hipLaunchKernelGGL(scatter_data_kernel, dim3(nblk), dim3(256), 0, stream,
                           aabb, points, normals, cnt_p, slots8, ovf_cnt, ovf, n);
        hipLaunchKernelGGL(main_data_kernel, dim3(NBINS), dim3(MAIN_THREADS),
                           LDS_F4 * sizeof(float4), stream,
                           coeff, aabb, points, normals, cnt_p, slots8, ovf_cnt, ovf, out, n);
    } else {
        int* slots = (int*)slots_base;
        hipLaunchKernelGGL(scatter_idx_kernel, dim3(nblk), dim3(256), 0, stream,
                           aabb, points, cnt_p, slots, ovf_cnt, ovf, n);
        hipLaunchKernelGGL(main_idx_kernel, dim3(NBINS), dim3(MAIN_THREADS),
                           LDS_F4 * sizeof(float4), stream,
                           coeff, aabb, points, normals, cnt_p, slots, ovf_cnt, ovf, out, n);
    }
}